// Round 6
// baseline (213.018 us; speedup 1.0000x reference)
//
#include <hip/hip_runtime.h>
#include <math.h>

#define S_LEN 512
#define BATCH 256
#define NTAG  128
#define EMSTRIDE (BATCH * NTAG)  /* floats per time step */

typedef float f32x4 __attribute__((ext_vector_type(4)));
typedef float f32x2 __attribute__((ext_vector_type(2)));

// LDS float index: 32-float k-slices padded by 4 -> slice h base = 36h floats,
// so the wave's 4 distinct broadcast addresses land on disjoint bank quads.
__device__ __forceinline__ int lidx(int k) { return (k & 31) + 36 * (k >> 5); }

__device__ __forceinline__ f32x2 lo2(f32x4 v){ f32x2 r; r[0]=v[0]; r[1]=v[1]; return r; }
__device__ __forceinline__ f32x2 hi2(f32x4 v){ f32x2 r; r[0]=v[2]; r[1]=v[3]; return r; }
__device__ __forceinline__ f32x2 pmax2(f32x2 a, f32x2 b){
  f32x2 r; r[0]=fmaxf(a[0],b[0]); r[1]=fmaxf(a[1],b[1]); return r;
}
__device__ __forceinline__ f32x2 fma2(f32x2 a, f32x2 b, f32x2 c){
  f32x2 r; r[0]=__builtin_fmaf(a[0],b[0],c[0]); r[1]=__builtin_fmaf(a[1],b[1],c[1]); return r;
}

// DPP quad-perm butterfly (intra-quad, VALU-speed)
#define DPP_XOR1(x) __int_as_float(__builtin_amdgcn_mov_dpp(__float_as_int(x), 0xB1, 0xF, 0xF, false))
#define DPP_XOR2(x) __int_as_float(__builtin_amdgcn_mov_dpp(__float_as_int(x), 0x4E, 0xF, 0xF, false))

// Raw barrier: drain LDS only (NOT vmcnt) so global prefetch stays in flight.
#define BAR() do {                                       \
    asm volatile("s_waitcnt lgkmcnt(0)" ::: "memory");   \
    __builtin_amdgcn_s_barrier();                        \
    __builtin_amdgcn_sched_barrier(0);                   \
  } while (0)

// ---------------------------------------------------------------------------
// Fat kernel, 128 threads/block, grid = 5*BATCH:
//   role = blk>>8: 0=fwd-left, 1=fwd-right(backward), 2=vit-left,
//                  3=vit-right(backward), 4=gold.  b = blk&255.
// Recurrence thread map: g = tid>>2 owns rows 4g..4g+3 (E/T rows in regs),
// h = tid&3 owns k-slice [32h,32h+32). Each state value is read ONCE per
// thread and reused for 4 rows -> 4x less LDS broadcast traffic than R5.
// Lane h of quad g writes row 4g+h == tid.
// ---------------------------------------------------------------------------
__global__ __launch_bounds__(128, 1)
void crf_fat_kernel(const float* __restrict__ emis,
                    const float* __restrict__ mask,
                    const int* __restrict__ tags,
                    const float* __restrict__ trans,
                    const float* __restrict__ startt,
                    const float* __restrict__ stopt,
                    float* __restrict__ ws,
                    int* __restrict__ ewbuf,
                    float* __restrict__ out)
{
  const int blk  = blockIdx.x;
  const int tid  = threadIdx.x;
  const int role = blk >> 8;
  const int b    = blk & 255;
  const int lane = tid & 63;
  const int wid  = tid >> 6;

  __shared__ __align__(16) float sbuf[2][144];
  __shared__ float red[8];

  // ---------------- gold role ----------------
  if (role == 4) {
    float part = 0.f, lenp = 0.f;
#pragma unroll
    for (int rep = 0; rep < 4; ++rep) {
      int s = tid + rep * 128;
      float m  = mask[(size_t)s * BATCH + b];
      int  cur = tags[(size_t)s * BATCH + b];
      if (s == 0) {
        part += startt[cur] + emis[(size_t)b * NTAG + cur] * m;
      } else {
        int prev = tags[(size_t)(s - 1) * BATCH + b];
        part += m * (trans[(size_t)prev * NTAG + cur] +
                     emis[((size_t)s * BATCH + b) * NTAG + cur]);
      }
      lenp += m;
    }
#pragma unroll
    for (int d = 1; d <= 32; d <<= 1) {
      part += __shfl_xor(part, d);
      lenp += __shfl_xor(lenp, d);
    }
    if (lane == 0) { red[wid] = part; red[2 + wid] = lenp; }
    __syncthreads();
    if (tid == 0) {
      float rps = red[0] + red[1];
      int len = (int)(red[2] + red[3] + 0.5f);
      int pf  = tags[(size_t)(len - 1) * BATCH + b];
      out[1 + b] = rps + stopt[pf];
    }
    return;
  }

  const int h    = tid & 3;
  const int g    = tid >> 2;
  const int bch  = 9 * h;          // f32x4 chunk base of my k-slice
  const int wloc = lidx(tid);      // my write slot (row tid)

  // ---- len = sum_s mask[s,b] (mask monotone) ----
  int len;
  {
    float mv = mask[(size_t)tid * BATCH + b] +
               mask[(size_t)(tid + 128) * BATCH + b] +
               mask[(size_t)(tid + 256) * BATCH + b] +
               mask[(size_t)(tid + 384) * BATCH + b];
#pragma unroll
    for (int d = 1; d <= 32; d <<= 1) mv += __shfl_xor(mv, d);
    if (lane == 0) red[wid] = mv;
    __syncthreads();
    len = (int)(red[0] + red[1] + 0.5f);
    len = __builtin_amdgcn_readfirstlane(len);
  }
  const int sm     = (len - 1) >> 1;
  const int nsteps = len - 1 - sm;     // backward step count
  const float* eb  = emis + (size_t)b * NTAG + tid;

  if (role == 0) {
    // ========== forward-left (exp space, rows of E) ==========
    f32x2 E2[4][16];
#pragma unroll
    for (int rr = 0; rr < 4; ++rr) {
      const float* tr = trans + (size_t)(4 * g + rr) * NTAG + 32 * h;
#pragma unroll
      for (int c = 0; c < 8; ++c) {
        f32x4 t = *(const f32x4*)(tr + 4 * c);
        f32x2 a, bb;
        a[0] = __expf(t[0]);  a[1] = __expf(t[1]);
        bb[0] = __expf(t[2]); bb[1] = __expf(t[3]);
        E2[rr][2*c] = a; E2[rr][2*c+1] = bb;
      }
    }
    sbuf[0][wloc] = __expf(startt[tid] + eb[0]);
    float e0 = eb[(size_t)1 * EMSTRIDE];
    float e1 = eb[(size_t)2 * EMSTRIDE];
    float e2 = eb[(size_t)3 * EMSTRIDE];
    float e3 = eb[(size_t)4 * EMSTRIDE];
    int Ew = 0, fin = 0;
    __syncthreads();

#define FSTEP(U, EMV, RENORM)                                                 \
  {                                                                           \
    if (g4 + (U) > sm) { fin = (U) & 1; goto epi_f; }                         \
    const f32x4* wr = (const f32x4*)sbuf[(U) & 1];                            \
    f32x2 a0={0.f,0.f}, a1={0.f,0.f}, a2={0.f,0.f}, a3={0.f,0.f};             \
    f32x2 r2={0.f,0.f};                                                       \
    _Pragma("unroll")                                                         \
    for (int c = 0; c < 8; ++c) {                                             \
      f32x4 w = wr[bch + c];                                                  \
      f32x2 wl = lo2(w), wh = hi2(w);                                         \
      a0 = fma2(E2[0][2*c], wl, a0); a0 = fma2(E2[0][2*c+1], wh, a0);         \
      a1 = fma2(E2[1][2*c], wl, a1); a1 = fma2(E2[1][2*c+1], wh, a1);         \
      a2 = fma2(E2[2][2*c], wl, a2); a2 = fma2(E2[2][2*c+1], wh, a2);         \
      a3 = fma2(E2[3][2*c], wl, a3); a3 = fma2(E2[3][2*c+1], wh, a3);         \
      if (RENORM) r2 = pmax2(r2, pmax2(wl, wh));                              \
    }                                                                         \
    float s0 = a0[0]+a0[1], s1 = a1[0]+a1[1];                                 \
    float s2 = a2[0]+a2[1], s3 = a3[0]+a3[1];                                 \
    s0 += DPP_XOR1(s0); s0 += DPP_XOR2(s0);                                   \
    s1 += DPP_XOR1(s1); s1 += DPP_XOR2(s1);                                   \
    s2 += DPP_XOR1(s2); s2 += DPP_XOR2(s2);                                   \
    s3 += DPP_XOR1(s3); s3 += DPP_XOR2(s3);                                   \
    float v01 = (h & 1) ? s1 : s0;                                            \
    float v23 = (h & 1) ? s3 : s2;                                            \
    float vs  = (h & 2) ? v23 : v01;                                          \
    float ex  = __expf(EMV);                                                  \
    float uf;                                                                 \
    if (RENORM) {                                                             \
      float rw = fmaxf(r2[0], r2[1]);                                         \
      rw = fmaxf(rw, DPP_XOR1(rw)); rw = fmaxf(rw, DPP_XOR2(rw));             \
      int ew = (int)((__float_as_uint(rw) >> 23) & 0xFF) - 126;               \
      Ew += ew;                                                               \
      float swc = __uint_as_float((unsigned)(127 - ew) << 23);                \
      uf = ex * vs * swc;                                                     \
    } else {                                                                  \
      uf = ex * vs;                                                           \
    }                                                                         \
    sbuf[((U) + 1) & 1][wloc] = uf;                                           \
    BAR();                                                                    \
  }

    for (int g4 = 1; g4 < S_LEN; g4 += 4) {
      int c0 = g4 + 4 < S_LEN ? g4 + 4 : S_LEN - 1;
      int c1 = g4 + 5 < S_LEN ? g4 + 5 : S_LEN - 1;
      int c2 = g4 + 6 < S_LEN ? g4 + 6 : S_LEN - 1;
      int c3 = g4 + 7 < S_LEN ? g4 + 7 : S_LEN - 1;
      float n0 = eb[(size_t)c0 * EMSTRIDE];
      float n1 = eb[(size_t)c1 * EMSTRIDE];
      float n2 = eb[(size_t)c2 * EMSTRIDE];
      float n3 = eb[(size_t)c3 * EMSTRIDE];
      FSTEP(0, e0, 0)
      FSTEP(1, e1, 0)
      FSTEP(2, e2, 0)
      FSTEP(3, e3, 1)   // renorm every 4th step (growth < 2^90, fp32-safe)
      e0 = n0; e1 = n1; e2 = n2; e3 = n3;
    }
    fin = 0;
epi_f:
    ws[(size_t)b * 512 + tid] = sbuf[fin][wloc];
    if (tid == 0) ewbuf[b] = Ew;
  } else if (role == 1) {
    // ========== forward-right / backward (exp space, columns of E) ==========
    f32x2 E2[4][16];
#pragma unroll
    for (int rr = 0; rr < 4; ++rr) {
      const float* tc = trans + (4 * g + rr) + (size_t)(32 * h) * NTAG;
#pragma unroll
      for (int q = 0; q < 16; ++q) {
        f32x2 a;
        a[0] = __expf(tc[(size_t)(2*q)     * NTAG]);
        a[1] = __expf(tc[(size_t)(2*q + 1) * NTAG]);
        E2[rr][q] = a;
      }
    }
    {
      float st = stopt[tid];
      sbuf[0][wloc] = (nsteps > 0) ? __expf(st + eb[(size_t)(len - 1) * EMSTRIDE])
                                   : __expf(st);
    }
    int s0i = len - 2; s0i = s0i < 0 ? 0 : s0i;
    int s1i = len - 3; s1i = s1i < 0 ? 0 : s1i;
    int s2i = len - 4; s2i = s2i < 0 ? 0 : s2i;
    int s3i = len - 5; s3i = s3i < 0 ? 0 : s3i;
    float e0 = eb[(size_t)s0i * EMSTRIDE];
    float e1 = eb[(size_t)s1i * EMSTRIDE];
    float e2 = eb[(size_t)s2i * EMSTRIDE];
    float e3 = eb[(size_t)s3i * EMSTRIDE];
    int Ew = 0, fin = 0;
    __syncthreads();

#define BSTEP(U, EMV, RENORM)                                                 \
  {                                                                           \
    if (gi + (U) >= nsteps) { fin = (U) & 1; goto epi_b; }                    \
    const f32x4* wr = (const f32x4*)sbuf[(U) & 1];                            \
    f32x2 a0={0.f,0.f}, a1={0.f,0.f}, a2={0.f,0.f}, a3={0.f,0.f};             \
    f32x2 r2={0.f,0.f};                                                       \
    _Pragma("unroll")                                                         \
    for (int c = 0; c < 8; ++c) {                                             \
      f32x4 w = wr[bch + c];                                                  \
      f32x2 wl = lo2(w), wh = hi2(w);                                         \
      a0 = fma2(E2[0][2*c], wl, a0); a0 = fma2(E2[0][2*c+1], wh, a0);         \
      a1 = fma2(E2[1][2*c], wl, a1); a1 = fma2(E2[1][2*c+1], wh, a1);         \
      a2 = fma2(E2[2][2*c], wl, a2); a2 = fma2(E2[2][2*c+1], wh, a2);         \
      a3 = fma2(E2[3][2*c], wl, a3); a3 = fma2(E2[3][2*c+1], wh, a3);         \
      if (RENORM) r2 = pmax2(r2, pmax2(wl, wh));                              \
    }                                                                         \
    float s0 = a0[0]+a0[1], s1 = a1[0]+a1[1];                                 \
    float s2 = a2[0]+a2[1], s3 = a3[0]+a3[1];                                 \
    s0 += DPP_XOR1(s0); s0 += DPP_XOR2(s0);                                   \
    s1 += DPP_XOR1(s1); s1 += DPP_XOR2(s1);                                   \
    s2 += DPP_XOR1(s2); s2 += DPP_XOR2(s2);                                   \
    s3 += DPP_XOR1(s3); s3 += DPP_XOR2(s3);                                   \
    float v01 = (h & 1) ? s1 : s0;                                            \
    float v23 = (h & 1) ? s3 : s2;                                            \
    float vs  = (h & 2) ? v23 : v01;                                          \
    float ex  = __expf(EMV);                                                  \
    float exm = (gi + (U) == nsteps - 1) ? 1.0f : ex;                         \
    float uf;                                                                 \
    if (RENORM) {                                                             \
      float rw = fmaxf(r2[0], r2[1]);                                         \
      rw = fmaxf(rw, DPP_XOR1(rw)); rw = fmaxf(rw, DPP_XOR2(rw));             \
      int ew = (int)((__float_as_uint(rw) >> 23) & 0xFF) - 126;               \
      Ew += ew;                                                               \
      float swc = __uint_as_float((unsigned)(127 - ew) << 23);                \
      uf = exm * vs * swc;                                                    \
    } else {                                                                  \
      uf = exm * vs;                                                          \
    }                                                                         \
    sbuf[((U) + 1) & 1][wloc] = uf;                                           \
    BAR();                                                                    \
  }

    for (int gi = 0; gi < S_LEN; gi += 4) {
      int c0 = len - 2 - (gi + 4); c0 = c0 < 0 ? 0 : c0;
      int c1 = len - 2 - (gi + 5); c1 = c1 < 0 ? 0 : c1;
      int c2 = len - 2 - (gi + 6); c2 = c2 < 0 ? 0 : c2;
      int c3 = len - 2 - (gi + 7); c3 = c3 < 0 ? 0 : c3;
      float n0 = eb[(size_t)c0 * EMSTRIDE];
      float n1 = eb[(size_t)c1 * EMSTRIDE];
      float n2 = eb[(size_t)c2 * EMSTRIDE];
      float n3 = eb[(size_t)c3 * EMSTRIDE];
      BSTEP(0, e0, 0)
      BSTEP(1, e1, 0)
      BSTEP(2, e2, 0)
      BSTEP(3, e3, 1)
      e0 = n0; e1 = n1; e2 = n2; e3 = n3;
    }
    fin = 0;
epi_b:
    ws[(size_t)b * 512 + 128 + tid] = sbuf[fin][wloc];
    if (tid == 0) ewbuf[BATCH + b] = Ew;
  } else if (role == 2) {
    // ========== viterbi-left (log space, rows of T) ==========
    f32x2 T2[4][16];
#pragma unroll
    for (int rr = 0; rr < 4; ++rr) {
      const float* tr = trans + (size_t)(4 * g + rr) * NTAG + 32 * h;
#pragma unroll
      for (int c = 0; c < 8; ++c) {
        f32x4 t = *(const f32x4*)(tr + 4 * c);
        T2[rr][2*c]   = lo2(t);
        T2[rr][2*c+1] = hi2(t);
      }
    }
    sbuf[0][wloc] = startt[tid] + eb[0];
    float e0 = eb[(size_t)1 * EMSTRIDE];
    float e1 = eb[(size_t)2 * EMSTRIDE];
    float e2 = eb[(size_t)3 * EMSTRIDE];
    float e3 = eb[(size_t)4 * EMSTRIDE];
    int fin = 0;
    __syncthreads();

#define VSTEP(U, EMV)                                                         \
  {                                                                           \
    if (g4 + (U) > sm) { fin = (U) & 1; goto epi_v; }                         \
    const f32x4* vr = (const f32x4*)sbuf[(U) & 1];                            \
    f32x2 m0={-3.0e38f,-3.0e38f}, m1={-3.0e38f,-3.0e38f};                     \
    f32x2 m2={-3.0e38f,-3.0e38f}, m3={-3.0e38f,-3.0e38f};                     \
    _Pragma("unroll")                                                         \
    for (int c = 0; c < 8; ++c) {                                             \
      f32x4 v = vr[bch + c];                                                  \
      f32x2 vl = lo2(v), vh = hi2(v);                                         \
      m0 = pmax2(m0, vl + T2[0][2*c]); m0 = pmax2(m0, vh + T2[0][2*c+1]);     \
      m1 = pmax2(m1, vl + T2[1][2*c]); m1 = pmax2(m1, vh + T2[1][2*c+1]);     \
      m2 = pmax2(m2, vl + T2[2][2*c]); m2 = pmax2(m2, vh + T2[2][2*c+1]);     \
      m3 = pmax2(m3, vl + T2[3][2*c]); m3 = pmax2(m3, vh + T2[3][2*c+1]);     \
    }                                                                         \
    float s0 = fmaxf(m0[0], m0[1]), s1 = fmaxf(m1[0], m1[1]);                 \
    float s2 = fmaxf(m2[0], m2[1]), s3 = fmaxf(m3[0], m3[1]);                 \
    s0 = fmaxf(s0, DPP_XOR1(s0)); s0 = fmaxf(s0, DPP_XOR2(s0));               \
    s1 = fmaxf(s1, DPP_XOR1(s1)); s1 = fmaxf(s1, DPP_XOR2(s1));               \
    s2 = fmaxf(s2, DPP_XOR1(s2)); s2 = fmaxf(s2, DPP_XOR2(s2));               \
    s3 = fmaxf(s3, DPP_XOR1(s3)); s3 = fmaxf(s3, DPP_XOR2(s3));               \
    float v01 = (h & 1) ? s1 : s0;                                            \
    float v23 = (h & 1) ? s3 : s2;                                            \
    float vs  = (h & 2) ? v23 : v01;                                          \
    sbuf[((U) + 1) & 1][wloc] = (EMV) + vs;                                   \
    BAR();                                                                    \
  }

    for (int g4 = 1; g4 < S_LEN; g4 += 4) {
      int c0 = g4 + 4 < S_LEN ? g4 + 4 : S_LEN - 1;
      int c1 = g4 + 5 < S_LEN ? g4 + 5 : S_LEN - 1;
      int c2 = g4 + 6 < S_LEN ? g4 + 6 : S_LEN - 1;
      int c3 = g4 + 7 < S_LEN ? g4 + 7 : S_LEN - 1;
      float n0 = eb[(size_t)c0 * EMSTRIDE];
      float n1 = eb[(size_t)c1 * EMSTRIDE];
      float n2 = eb[(size_t)c2 * EMSTRIDE];
      float n3 = eb[(size_t)c3 * EMSTRIDE];
      VSTEP(0, e0)
      VSTEP(1, e1)
      VSTEP(2, e2)
      VSTEP(3, e3)
      e0 = n0; e1 = n1; e2 = n2; e3 = n3;
    }
    fin = 0;
epi_v:
    ws[(size_t)b * 512 + 256 + tid] = sbuf[fin][wloc];
  } else {
    // ========== viterbi-right / backward (log space, columns of T) ==========
    f32x2 T2[4][16];
#pragma unroll
    for (int rr = 0; rr < 4; ++rr) {
      const float* tc = trans + (4 * g + rr) + (size_t)(32 * h) * NTAG;
#pragma unroll
      for (int q = 0; q < 16; ++q) {
        f32x2 a;
        a[0] = tc[(size_t)(2*q)     * NTAG];
        a[1] = tc[(size_t)(2*q + 1) * NTAG];
        T2[rr][q] = a;
      }
    }
    {
      float st = stopt[tid];
      sbuf[0][wloc] = (nsteps > 0) ? st + eb[(size_t)(len - 1) * EMSTRIDE] : st;
    }
    int s0i = len - 2; s0i = s0i < 0 ? 0 : s0i;
    int s1i = len - 3; s1i = s1i < 0 ? 0 : s1i;
    int s2i = len - 4; s2i = s2i < 0 ? 0 : s2i;
    int s3i = len - 5; s3i = s3i < 0 ? 0 : s3i;
    float e0 = eb[(size_t)s0i * EMSTRIDE];
    float e1 = eb[(size_t)s1i * EMSTRIDE];
    float e2 = eb[(size_t)s2i * EMSTRIDE];
    float e3 = eb[(size_t)s3i * EMSTRIDE];
    int fin = 0;
    __syncthreads();

#define WSTEP(U, EMV)                                                         \
  {                                                                           \
    if (gi + (U) >= nsteps) { fin = (U) & 1; goto epi_w; }                    \
    const f32x4* vr = (const f32x4*)sbuf[(U) & 1];                            \
    f32x2 m0={-3.0e38f,-3.0e38f}, m1={-3.0e38f,-3.0e38f};                     \
    f32x2 m2={-3.0e38f,-3.0e38f}, m3={-3.0e38f,-3.0e38f};                     \
    _Pragma("unroll")                                                         \
    for (int c = 0; c < 8; ++c) {                                             \
      f32x4 v = vr[bch + c];                                                  \
      f32x2 vl = lo2(v), vh = hi2(v);                                         \
      m0 = pmax2(m0, vl + T2[0][2*c]); m0 = pmax2(m0, vh + T2[0][2*c+1]);     \
      m1 = pmax2(m1, vl + T2[1][2*c]); m1 = pmax2(m1, vh + T2[1][2*c+1]);     \
      m2 = pmax2(m2, vl + T2[2][2*c]); m2 = pmax2(m2, vh + T2[2][2*c+1]);     \
      m3 = pmax2(m3, vl + T2[3][2*c]); m3 = pmax2(m3, vh + T2[3][2*c+1]);     \
    }                                                                         \
    float s0 = fmaxf(m0[0], m0[1]), s1 = fmaxf(m1[0], m1[1]);                 \
    float s2 = fmaxf(m2[0], m2[1]), s3 = fmaxf(m3[0], m3[1]);                 \
    s0 = fmaxf(s0, DPP_XOR1(s0)); s0 = fmaxf(s0, DPP_XOR2(s0));               \
    s1 = fmaxf(s1, DPP_XOR1(s1)); s1 = fmaxf(s1, DPP_XOR2(s1));               \
    s2 = fmaxf(s2, DPP_XOR1(s2)); s2 = fmaxf(s2, DPP_XOR2(s2));               \
    s3 = fmaxf(s3, DPP_XOR1(s3)); s3 = fmaxf(s3, DPP_XOR2(s3));               \
    float v01 = (h & 1) ? s1 : s0;                                            \
    float v23 = (h & 1) ? s3 : s2;                                            \
    float vs  = (h & 2) ? v23 : v01;                                          \
    float uv  = (gi + (U) == nsteps - 1) ? vs : vs + (EMV);                   \
    sbuf[((U) + 1) & 1][wloc] = uv;                                           \
    BAR();                                                                    \
  }

    for (int gi = 0; gi < S_LEN; gi += 4) {
      int c0 = len - 2 - (gi + 4); c0 = c0 < 0 ? 0 : c0;
      int c1 = len - 2 - (gi + 5); c1 = c1 < 0 ? 0 : c1;
      int c2 = len - 2 - (gi + 6); c2 = c2 < 0 ? 0 : c2;
      int c3 = len - 2 - (gi + 7); c3 = c3 < 0 ? 0 : c3;
      float n0 = eb[(size_t)c0 * EMSTRIDE];
      float n1 = eb[(size_t)c1 * EMSTRIDE];
      float n2 = eb[(size_t)c2 * EMSTRIDE];
      float n3 = eb[(size_t)c3 * EMSTRIDE];
      WSTEP(0, e0)
      WSTEP(1, e1)
      WSTEP(2, e2)
      WSTEP(3, e3)
      e0 = n0; e1 = n1; e2 = n2; e3 = n3;
    }
    fin = 0;
epi_w:
    ws[(size_t)b * 512 + 384 + tid] = sbuf[fin][wloc];
  }
}

// ---------------------------------------------------------------------------
// Combine: total = (EwF+EwB)ln2 + log(sum_k WF*WB); best = max_k(VF+VB).
// ---------------------------------------------------------------------------
__global__ __launch_bounds__(128, 1)
void crf_combine_kernel(const float* __restrict__ ws,
                        const int* __restrict__ ewbuf,
                        float* __restrict__ out)
{
  const int b = blockIdx.x, k = threadIdx.x;
  const float* base = ws + (size_t)b * 512;
  float t1 = base[k] * base[128 + k];
  float m1 = base[256 + k] + base[384 + k];
#pragma unroll
  for (int d = 1; d <= 32; d <<= 1) {
    t1 += __shfl_xor(t1, d);
    m1 = fmaxf(m1, __shfl_xor(m1, d));
  }
  __shared__ float rs[2], rm[2];
  const int lane = k & 63, wid = k >> 6;
  if (lane == 0) { rs[wid] = t1; rm[wid] = m1; }
  __syncthreads();
  if (k == 0) {
    const double LN2 = 0.6931471805599453;
    int Et = ewbuf[b] + ewbuf[BATCH + b];
    out[1 + BATCH + b]     = (float)((double)Et * LN2 + (double)__logf(rs[0] + rs[1]));
    out[1 + 2 * BATCH + b] = fmaxf(rm[0], rm[1]);
  }
}

// ---------------------------------------------------------------------------
// loss = mean(total_score - real_path_score)
// ---------------------------------------------------------------------------
__global__ __launch_bounds__(256, 1)
void crf_loss_kernel(float* __restrict__ out)
{
  const int tid = threadIdx.x;
  float dft = out[1 + BATCH + tid] - out[1 + tid];
#pragma unroll
  for (int d = 1; d <= 32; d <<= 1) dft += __shfl_xor(dft, d);
  __shared__ float rs[4];
  const int lane = tid & 63, wid = tid >> 6;
  if (lane == 0) rs[wid] = dft;
  __syncthreads();
  if (tid == 0)
    out[0] = ((rs[0] + rs[1]) + (rs[2] + rs[3])) * (1.0f / BATCH);
}

extern "C" void kernel_launch(void* const* d_in, const int* in_sizes, int n_in,
                              void* d_out, int out_size, void* d_ws, size_t ws_size,
                              hipStream_t stream)
{
  const float* emis   = (const float*)d_in[0];
  const float* mask   = (const float*)d_in[1];
  const int*   tags   = (const int*)d_in[2];
  const float* trans  = (const float*)d_in[3];
  const float* startt = (const float*)d_in[4];
  const float* stopt  = (const float*)d_in[5];
  float* out = (float*)d_out;

  float* wsf   = (float*)d_ws;                 // 256 * 512 floats
  int*   ewbuf = (int*)(wsf + 512 * BATCH);    // 2 * 256 ints

  crf_fat_kernel<<<5 * BATCH, 128, 0, stream>>>(emis, mask, tags, trans,
                                                startt, stopt, wsf, ewbuf, out);
  crf_combine_kernel<<<BATCH, 128, 0, stream>>>(wsf, ewbuf, out);
  crf_loss_kernel<<<1, 256, 0, stream>>>(out);
}